// Round 3
// baseline (84.888 us; speedup 1.0000x reference)
//
#include <hip/hip_runtime.h>

#define N_EVAL 2001
#define NCTRL  64
#define ROWF   6003            // floats per u-row; 6003 % 4 == 3
#define RPB    4               // rows per block; 4*6003 = 24012 ≡ 0 (mod 4)
#define TPB    512
#define GROUPF (RPB * ROWF)    // 24012 floats per block group, 16B-aligned start

// degree p = 3; clamped knots: [0,0,0,0, 1/61..60/61, 1,1,1,1] (len 68)
__device__ __forceinline__ float knotv(int i) {
    if (i <= 3) return 0.0f;
    if (i >= NCTRL) return 1.0f;
    return (float)(i - 3) * (1.0f / 61.0f);
}

// Cox-de-Boor degree 3, searchsorted(side='right') span semantics (exact divides)
__device__ __forceinline__ void basis_p3(float u, int& span, float* Ns) {
    int s = 3 + (int)floorf(u * 61.0f);
    s = max(3, min(63, s));
    while (s < 63 && knotv(s + 1) <= u) ++s;
    while (s > 3 && knotv(s) > u) --s;
    float left[4], right[4];
    Ns[0] = 1.0f;
    #pragma unroll
    for (int j = 1; j <= 3; ++j) {
        left[j]  = u - knotv(s + 1 - j);
        right[j] = knotv(s + j) - u;
        float saved = 0.0f;
        #pragma unroll
        for (int r = 0; r < j; ++r) {
            float temp = Ns[r] / (right[r + 1] + left[j - r]);
            Ns[r] = saved + right[r + 1] * temp;
            saved = left[j - r] * temp;
        }
        Ns[j] = saved;
    }
    span = s;
}

__global__ void basis_kernel(const float* __restrict__ pu, const float* __restrict__ pv,
                             float4* __restrict__ Bu4, int* __restrict__ su,
                             float4* __restrict__ bvp) {
    int gid = blockIdx.x * blockDim.x + threadIdx.x;
    if (gid >= N_EVAL) return;
    int s; float N[4];
    basis_p3(pu[gid], s, N);
    Bu4[gid] = make_float4(N[0], N[1], N[2], N[3]);
    su[gid] = s;
    int s2; float M[4];
    basis_p3(pv[gid], s2, M);
    // packed: b3 reconstructed as 1-b0-b1-b2 (partition of unity, ~1e-7 err)
    bvp[gid] = make_float4(M[0], M[1], M[2], (float)s2);
}

// point eval from packed basis against an LDS curve row
__device__ __forceinline__ float3 eval_pt(const float4* __restrict__ curve, float4 q) {
    float b3 = 1.0f - q.x - q.y - q.z;
    int iv0 = (int)q.w - 3;              // span-3 in [0,60]
    float4 c0 = curve[iv0 + 0];
    float4 c1 = curve[iv0 + 1];
    float4 c2 = curve[iv0 + 2];
    float4 c3 = curve[iv0 + 3];
    return make_float3(q.x * c0.x + q.y * c1.x + q.z * c2.x + b3 * c3.x,
                       q.x * c0.y + q.y * c1.y + q.z * c2.y + b3 * c3.y,
                       q.x * c0.z + q.y * c1.z + q.z * c2.z + b3 * c3.z);
}

// 4 u-rows per block. Group of 4 rows = 24012 floats ≡ 0 mod 4 → every block's
// output region is 16B-aligned with NO head/tail: uniform float4 slots only.
// Row-straddling slots (3 per block) are handled by the same two-point decode:
// first point from (f/6003), second from ((f+3)/6003) — no branches.
__global__ __launch_bounds__(TPB) void eval_kernel(const float* __restrict__ cp,
                                                   const float4* __restrict__ Bu4,
                                                   const int* __restrict__ su,
                                                   const float4* __restrict__ bvp,
                                                   float* __restrict__ out) {
    __shared__ float4 curve[RPB * NCTRL];   // 4 u-contracted rows: (x,y,z,pad) per j

    const int b = blockIdx.x;
    const int t = threadIdx.x;
    const int u0 = b * RPB;
    const int nrows = min(RPB, N_EVAL - u0);   // 4, except tail block: 1

    // ---- stage nrows curves: nrows*192 staging slots over 512 threads (2 passes)
    #pragma unroll
    for (int pass = 0; pass < 2; ++pass) {
        const int w = t + pass * TPB;
        if (w < nrows * (NCTRL * 3)) {
            const int r   = w / (NCTRL * 3);
            const int idx = w - r * (NCTRL * 3);
            const float4 bu = Bu4[u0 + r];
            const int  s_u  = su[u0 + r];
            const int base  = (s_u - 3) * (NCTRL * 3);
            float c = bu.x * cp[base +       idx]
                    + bu.y * cp[base + 192 + idx]
                    + bu.z * cp[base + 384 + idx]
                    + bu.w * cp[base + 576 + idx];
            const int j = idx / 3, d = idx - 3 * j;
            ((float*)curve)[(r * NCTRL + j) * 4 + d] = c;
        }
    }
    __syncthreads();                      // the only barrier

    const size_t G = (size_t)b * GROUPF;  // group float base, ≡ 0 mod 4
    float4* outv = (float4*)(out + G);
    const int totalF    = nrows * ROWF;     // 24012 or 6003
    const int fullSlots = totalF >> 2;      // 6003 or 1500

    #pragma unroll
    for (int k = 0; k < 12; ++k) {
        const int s = k * TPB + t;
        if (s < fullSlots) {
            const int f   = 4 * s;              // group-local float index
            const int g1  = f + 3;
            const int r0  = f  / ROWF;          // row of first float
            const int fr0 = f  - r0 * ROWF;
            const int r1  = g1 / ROWF;          // row of last float (straddle-aware)
            const int fr1 = g1 - r1 * ROWF;
            const int v0  = fr0 / 3;
            const int ph  = fr0 - 3 * v0;       // 0,1,2
            const int v1  = fr1 / 3;            // v0+1 normally; 0 on row straddle
            const float4 q0 = bvp[v0];
            const float4 q1 = bvp[v1];
            const float3 P0 = eval_pt(curve + r0 * NCTRL, q0);
            const float3 P1 = eval_pt(curve + r1 * NCTRL, q1);
            float4 rr;
            if (ph == 0)      rr = make_float4(P0.x, P0.y, P0.z, P1.x);
            else if (ph == 1) rr = make_float4(P0.y, P0.z, P1.x, P1.y);
            else              rr = make_float4(P0.z, P1.x, P1.y, P1.z);
            outv[s] = rr;                       // contiguous, always aligned
        }
    }

    // leftover floats: only the tail block (totalF % 4 == 3)
    const int leftover = totalF - 4 * fullSlots;
    if (t < leftover) {
        const int g    = 4 * fullSlots + t;
        const int r    = g / ROWF;
        const int fr   = g - r * ROWF;
        const int v    = fr / 3;
        const int comp = fr - 3 * v;
        const float3 P = eval_pt(curve + r * NCTRL, bvp[v]);
        out[G + g] = (comp == 0) ? P.x : (comp == 1 ? P.y : P.z);
    }
}

extern "C" void kernel_launch(void* const* d_in, const int* in_sizes, int n_in,
                              void* d_out, int out_size, void* d_ws, size_t ws_size,
                              hipStream_t stream) {
    const float* cp = (const float*)d_in[0];   // [64,64,3] f32
    const float* pu = (const float*)d_in[1];   // [2001] f32
    const float* pv = (const float*)d_in[2];   // [2001] f32
    float* out = (float*)d_out;                // [2001,2001,3] f32

    // ws: Bu4 f4[2001] | bvp f4[2001] | su i32[2001]  (~72 KB)
    float4* Bu4 = (float4*)d_ws;
    float4* bvp = Bu4 + N_EVAL;
    int* su = (int*)(bvp + N_EVAL);

    basis_kernel<<<8, 256, 0, stream>>>(pu, pv, Bu4, su, bvp);

    const int nblocks = (N_EVAL + RPB - 1) / RPB;   // 501
    eval_kernel<<<nblocks, TPB, 0, stream>>>(cp, Bu4, su, bvp, out);
}